// Round 1
// baseline (731.826 us; speedup 1.0000x reference)
//
#include <hip/hip_runtime.h>
#include <hip/hip_bf16.h>

// Problem constants
#define B_    8
#define DIM   256
#define HH    160
#define WW_   160
#define NHEAD 8
#define HD    32
#define P_    4
#define WP_   40      // windows per row/col (160/4)
#define NPW   1600    // windows per batch image (40*40)
#define PP    16      // tokens per window (4*4)

// att workspace geometry: rows R = ((b*40+hp)*4+ph)*160 + w  (w-ordered!)
#define NROWS 204800          // 8*40*4*160
#define HSTRIDE 6553600L      // NROWS*32 elements per head plane

typedef __attribute__((ext_vector_type(8))) short bf16x8;
typedef __attribute__((ext_vector_type(4))) float f32x4;

__device__ __forceinline__ unsigned short f2b(float f) {
    __hip_bfloat16 h = __float2bfloat16(f);
    return *(unsigned short*)&h;
}

// Pre-convert out_w (fp32 [256][256]) -> bf16 in workspace.
__global__ void convert_w_kernel(const float* __restrict__ w,
                                 short* __restrict__ wb)
{
    const int i = blockIdx.x * 256 + threadIdx.x;   // 16384 threads, 4 elems each
    float4 v = ((const float4*)w)[i];
    short4 o;
    o.x = (short)f2b(v.x); o.y = (short)f2b(v.y);
    o.z = (short)f2b(v.z); o.w = (short)f2b(v.w);
    ((short4*)wb)[i] = o;
}

// ============================================================================
// Phase 1: attention. One block = (b, hp, head, wg) covering 8 windows
// (32 contiguous pixel cols -> 128B-coalesced x loads).
// 128 threads: exactly one (win, pos) task per thread.
// Algebraic folds:  s_ij = sum_d (scale*q_i_d*wk_d) x_j_d + sum_d scale*q_i_d*bk_d
//                   att_d = wv_d * (sum_j p_j x_j_d) + bv_d   (sum_j p_j == 1)
// Output: bf16 att[head][R][d], R w-ordered. Thread writes 64B contiguous;
// this is exactly the MFMA B-fragment layout phase 2 consumes.
// ============================================================================
__launch_bounds__(128, 2)
__global__ void attn_kernel(const float* __restrict__ x,
                            const float* __restrict__ qkv_w,
                            const float* __restrict__ qkv_b,
                            const float* __restrict__ pos_encode,
                            const int* __restrict__ pos_index,
                            short* __restrict__ att)
{
    __shared__ float xs[4096];   // [c=32][r=4][col=32], linear, conflict-free
    __shared__ float wqs[32], bqs[32], wks[32], bks[32], wvs[32], bvs[32];
    __shared__ float bias[256];  // [i][j] for this head

    const int t   = threadIdx.x;
    const int blk = blockIdx.x;
    const int wg  = blk % 5;
    int tmp = blk / 5;
    const int head = tmp & 7; tmp >>= 3;
    const int hp = tmp % 40;
    const int b  = tmp / 40;
    const int c0 = head * 32;
    const int h0 = hp * 4;
    const int w0 = wg * 32;

    if (t < 32) {
        wqs[t] = qkv_w[c0 + t];       bqs[t] = qkv_b[c0 + t];
        wks[t] = qkv_w[256 + c0 + t]; bks[t] = qkv_b[256 + c0 + t];
        wvs[t] = qkv_w[512 + c0 + t]; bvs[t] = qkv_b[512 + c0 + t];
    }
    bias[t]       = pos_encode[pos_index[t] * 8 + head];
    bias[t + 128] = pos_encode[pos_index[t + 128] * 8 + head];

    // Stage x: 1024 float4 tasks; 128B contiguous runs in global, linear in LDS.
    #pragma unroll
    for (int it = 0; it < 8; ++it) {
        const int idx  = t + it * 128;         // 0..1023
        const int c    = idx >> 5;             // channel within head
        const int r    = (idx >> 3) & 3;       // patch row
        const int col4 = idx & 7;              // float4 within 32 cols
        const float4 v = *(const float4*)(x +
            (((long)(b * 256 + c0 + c) * 160) + h0 + r) * 160 + w0 + col4 * 4);
        *(float4*)&xs[idx * 4] = v;
    }
    __syncthreads();

    const int win = t >> 4, i = t & 15;
    const int iph = i >> 2, ipw = i & 3;
    const float scale = 0.17677669529663687f;  // 32^-0.5

    // q-row prep with wk folded in
    float qk[32]; float qbk = 0.f;
    {
        const int qb = iph * 32 + win * 4 + ipw;
        #pragma unroll
        for (int d = 0; d < 32; ++d) {
            const float q = (xs[d * 128 + qb] * wqs[d] + bqs[d]) * scale;
            qk[d] = q * wks[d];
            qbk  += q * bks[d];
        }
    }

    // scores + bias (k-row reads are 16-lane LDS broadcasts -> conflict-free)
    float s[16];
    #pragma unroll
    for (int j = 0; j < 16; ++j) {
        const int jb = (j >> 2) * 32 + win * 4 + (j & 3);
        float acc = qbk;
        #pragma unroll
        for (int d = 0; d < 32; ++d) acc += qk[d] * xs[d * 128 + jb];
        s[j] = acc + bias[i * 16 + j];
    }

    // softmax
    float m = s[0];
    #pragma unroll
    for (int j = 1; j < 16; ++j) m = fmaxf(m, s[j]);
    float l = 0.f;
    #pragma unroll
    for (int j = 0; j < 16; ++j) { s[j] = __expf(s[j] - m); l += s[j]; }
    const float inv = 1.f / l;

    // PV with wv fold; pack to bf16 pairs
    unsigned int ow[16];
    #pragma unroll
    for (int d2 = 0; d2 < 16; ++d2) {
        const int d0 = d2 * 2;
        float a0 = 0.f, a1 = 0.f;
        #pragma unroll
        for (int j = 0; j < 16; ++j) {
            const int jb = (j >> 2) * 32 + win * 4 + (j & 3);
            a0 += s[j] * xs[d0 * 128 + jb];
            a1 += s[j] * xs[d0 * 128 + 128 + jb];
        }
        a0 = a0 * inv * wvs[d0]     + bvs[d0];
        a1 = a1 * inv * wvs[d0 + 1] + bvs[d0 + 1];
        ow[d2] = (unsigned int)f2b(a0) | ((unsigned int)f2b(a1) << 16);
    }

    // 64B contiguous store per thread; wave covers 256B runs
    const int  R    = ((b * 40 + hp) * 4 + iph) * 160 + w0 + win * 4 + ipw;
    short* dst = att + (long)head * HSTRIDE + (long)R * 32;
    uint4 v0 = {ow[0],  ow[1],  ow[2],  ow[3]};
    uint4 v1 = {ow[4],  ow[5],  ow[6],  ow[7]};
    uint4 v2 = {ow[8],  ow[9],  ow[10], ow[11]};
    uint4 v3 = {ow[12], ow[13], ow[14], ow[15]};
    *(uint4*)(dst +  0) = v0;
    *(uint4*)(dst +  8) = v1;
    *(uint4*)(dst + 16) = v2;
    *(uint4*)(dst + 24) = v3;
}

// ============================================================================
// Phase 2: 1x1 conv as GEMM, computing Y^T tiles: D[o][w] so the lane-fast
// D dim is w -> coalesced stores. A = W (held in 128 VGPRs), B = att from
// workspace (1KB fully-coalesced fragment loads, no LDS).
// Block = (strip s = b*40+hp, og = 64-out-channel group); XCD-swizzled so the
// 4 og-blocks of one strip share an XCD L2 (att strip read once per XCD).
// Wave = one ph row (160 w), 10 chunks of 16 w.
// ============================================================================
__launch_bounds__(256, 2)
__global__ void conv_kernel(const short* __restrict__ att,
                            const short* __restrict__ wb,
                            float* __restrict__ y)
{
    const int blk = blockIdx.x;
    // blk = sh*32 + og*8 + sl ; s = sh*8 + sl  (keeps og-blocks of a strip on one XCD)
    const int sl = blk & 7;
    const int og = (blk >> 3) & 3;
    const int sh = blk >> 5;
    const int s  = sh * 8 + sl;          // 0..319
    const int b  = s / 40;
    const int hp = s % 40;

    const int t    = threadIdx.x;
    const int ph   = t >> 6;             // wave id = patch row
    const int lane = t & 63;
    const int m16  = lane & 15;
    const int kq   = lane >> 4;

    // W fragments: A[o_local = m16][k], 8 contiguous k at kq*8, per (nt, kk)
    bf16x8 wfr[4][8];
    #pragma unroll
    for (int nt = 0; nt < 4; ++nt)
        #pragma unroll
        for (int kk = 0; kk < 8; ++kk)
            wfr[nt][kk] = *(const bf16x8*)(wb +
                ((og * 64 + nt * 16 + m16) * 256 + kk * 32 + kq * 8));

    const int  R0   = s * 640 + ph * 160;         // strip row base for this wave
    const short* arow = att + (long)(R0 + m16) * 32 + kq * 8;  // + kk*HSTRIDE + cc*512
    float* yo = y + ((long)(b * 256 + og * 64) * 160 + (hp * 4 + ph)) * 160;

    const f32x4 zf = {0.f, 0.f, 0.f, 0.f};
    bf16x8 bA[8], bB[8];

#define LB(dstb, cc_) { \
    _Pragma("unroll") \
    for (int kk = 0; kk < 8; ++kk) \
        dstb[kk] = *(const bf16x8*)(arow + kk * HSTRIDE + (cc_) * 512); }

#define COMP(bfb, cc_) { \
    f32x4 a0 = zf, a1 = zf, a2 = zf, a3 = zf; \
    _Pragma("unroll") \
    for (int kk = 0; kk < 8; ++kk) { \
        a0 = __builtin_amdgcn_mfma_f32_16x16x32_bf16(wfr[0][kk], bfb[kk], a0, 0, 0, 0); \
        a1 = __builtin_amdgcn_mfma_f32_16x16x32_bf16(wfr[1][kk], bfb[kk], a1, 0, 0, 0); \
        a2 = __builtin_amdgcn_mfma_f32_16x16x32_bf16(wfr[2][kk], bfb[kk], a2, 0, 0, 0); \
        a3 = __builtin_amdgcn_mfma_f32_16x16x32_bf16(wfr[3][kk], bfb[kk], a3, 0, 0, 0); \
    } \
    _Pragma("unroll") \
    for (int r = 0; r < 4; ++r) { \
        const int oo = kq * 4 + r; \
        yo[(long)(oo     ) * 25600 + (cc_) * 16 + m16] = a0[r]; \
        yo[(long)(oo + 16) * 25600 + (cc_) * 16 + m16] = a1[r]; \
        yo[(long)(oo + 32) * 25600 + (cc_) * 16 + m16] = a2[r]; \
        yo[(long)(oo + 48) * 25600 + (cc_) * 16 + m16] = a3[r]; \
    } }

    LB(bA, 0);
    #pragma unroll
    for (int c2 = 0; c2 < 5; ++c2) {
        LB(bB, 2 * c2 + 1);
        COMP(bA, 2 * c2);
        if (c2 < 4) LB(bA, 2 * c2 + 2);
        COMP(bB, 2 * c2 + 1);
    }
#undef LB
#undef COMP
}

// ============================================================================
// Fallback (previous verified kernel) — used if workspace is too small for
// the 100 MB att buffer. One block = one (batch, window).
// ============================================================================
__launch_bounds__(256, 2)
__global__ void patchsa_fused(const float* __restrict__ x,
                              const float* __restrict__ qkv_w,
                              const float* __restrict__ qkv_b,
                              const float* __restrict__ pos_encode,
                              const short* __restrict__ w_bf16,
                              const int* __restrict__ pos_index,
                              float* __restrict__ y)
{
    __shared__ float wql[768];
    __shared__ float bql[768];
    __shared__ float pel[392];
    __shared__ int   pil[256];
    __shared__ float q4[NHEAD * 528];
    __shared__ float k4[NHEAD * 528];
    __shared__ float v4[NHEAD * 528];
    __shared__ float probs[2048];
    __shared__ alignas(16) short att3[4096];

    const int t   = threadIdx.x;
    const int blk = blockIdx.x;
    const int b   = blk / NPW;
    const int n   = blk % NPW;
    const int hp  = n / WP_;
    const int wp  = n % WP_;
    const int h0  = hp * P_;
    const int w0  = wp * P_;

    for (int idx = t; idx < 768; idx += 256) {
        wql[idx] = qkv_w[idx];
        bql[idx] = qkv_b[idx];
    }
    for (int idx = t; idx < 392; idx += 256)
        pel[idx] = pos_encode[idx];
    pil[t] = pos_index[t];
    __syncthreads();

    for (int task = t; task < 1024; task += 256) {
        const int c  = task & 255;
        const int ph = task >> 8;
        const float* xr = x + ((((long)b * DIM + c) * HH) + h0 + ph) * WW_ + w0;
        float4 xv = *(const float4*)xr;
        const int head = c >> 5, d = c & 31;
        const float wq = wql[c],      bq = bql[c];
        const float wk = wql[256+c],  bk = bql[256+c];
        const float wv = wql[512+c],  bv = bql[512+c];
        const int base = head * 528 + d;
        const int p0 = ph * 4;
        float xf[4] = {xv.x, xv.y, xv.z, xv.w};
        #pragma unroll
        for (int pw = 0; pw < 4; ++pw) {
            const int off = base + (p0 + pw) * 33;
            q4[off] = xf[pw] * wq + bq;
            k4[off] = xf[pw] * wk + bk;
            v4[off] = xf[pw] * wv + bv;
        }
    }
    __syncthreads();

    if (t < 128) {
        const int head = t >> 4, i = t & 15;
        const float scale = 0.17677669529663687f;
        float qr[32];
        const int qb = head * 528 + i * 33;
        #pragma unroll
        for (int d = 0; d < 32; ++d) qr[d] = q4[qb + d];
        float s[16];
        #pragma unroll
        for (int j = 0; j < 16; ++j) {
            const int kb = head * 528 + j * 33;
            float acc = 0.f;
            #pragma unroll
            for (int d = 0; d < 32; ++d) acc += qr[d] * k4[kb + d];
            s[j] = acc * scale + pel[pil[i * 16 + j] * NHEAD + head];
        }
        float m = s[0];
        #pragma unroll
        for (int j = 1; j < 16; ++j) m = fmaxf(m, s[j]);
        float l = 0.f;
        #pragma unroll
        for (int j = 0; j < 16; ++j) { s[j] = __expf(s[j] - m); l += s[j]; }
        const float inv = 1.f / l;
        #pragma unroll
        for (int j = 0; j < 16; ++j)
            probs[(head * 16 + i) * 16 + j] = s[j] * inv;
    }
    __syncthreads();

    {
        const int head = t >> 5, d = t & 31;
        float vr[16];
        const int vb = head * 528 + d;
        #pragma unroll
        for (int j = 0; j < 16; ++j) vr[j] = v4[vb + j * 33];
        const int k = t;
        const int abase = (k >> 3) * 128 + (k & 7);
        #pragma unroll
        for (int i = 0; i < 16; ++i) {
            const float* pr = &probs[(head * 16 + i) * 16];
            float acc = 0.f;
            #pragma unroll
            for (int j = 0; j < 16; ++j) acc += pr[j] * vr[j];
            att3[abase + i * 8] = (short)f2b(acc);
        }
    }
    __syncthreads();

    {
        const int wave = t >> 6, lane = t & 63;
        const int m16  = lane & 15, kq = lane >> 4;
        const int nbase = wave * 64;
        f32x4 acc0 = {0.f, 0.f, 0.f, 0.f};
        f32x4 acc1 = acc0, acc2 = acc0, acc3 = acc0;
        #pragma unroll
        for (int kk = 0; kk < 8; ++kk) {
            const int k0 = kk * 32 + kq * 8;
            bf16x8 a = *(const bf16x8*)&att3[(k0 >> 3) * 128 + m16 * 8];
            bf16x8 b0 = *(const bf16x8*)&w_bf16[(nbase +  0 + m16) * 256 + k0];
            bf16x8 b1 = *(const bf16x8*)&w_bf16[(nbase + 16 + m16) * 256 + k0];
            bf16x8 b2 = *(const bf16x8*)&w_bf16[(nbase + 32 + m16) * 256 + k0];
            bf16x8 b3 = *(const bf16x8*)&w_bf16[(nbase + 48 + m16) * 256 + k0];
            acc0 = __builtin_amdgcn_mfma_f32_16x16x32_bf16(a, b0, acc0, 0, 0, 0);
            acc1 = __builtin_amdgcn_mfma_f32_16x16x32_bf16(a, b1, acc1, 0, 0, 0);
            acc2 = __builtin_amdgcn_mfma_f32_16x16x32_bf16(a, b2, acc2, 0, 0, 0);
            acc3 = __builtin_amdgcn_mfma_f32_16x16x32_bf16(a, b3, acc3, 0, 0, 0);
        }
        f32x4 accs[4] = {acc0, acc1, acc2, acc3};
        #pragma unroll
        for (int nt = 0; nt < 4; ++nt) {
            const int o = nbase + nt * 16 + m16;
            const long ob = (((long)b * DIM + o) * HH) * WW_;
            #pragma unroll
            for (int r = 0; r < 4; ++r) {
                const int pos = kq * 4 + r;
                const int ph = pos >> 2, pw = pos & 3;
                y[ob + (long)(h0 + ph) * WW_ + (w0 + pw)] = accs[nt][r];
            }
        }
    }
}

extern "C" void kernel_launch(void* const* d_in, const int* in_sizes, int n_in,
                              void* d_out, int out_size, void* d_ws, size_t ws_size,
                              hipStream_t stream) {
    const float* x          = (const float*)d_in[0];
    const float* qkv_w      = (const float*)d_in[1];
    const float* qkv_b      = (const float*)d_in[2];
    const float* pos_encode = (const float*)d_in[3];
    const float* out_w      = (const float*)d_in[4];
    const int*   pos_index  = (const int*)d_in[5];
    float* y = (float*)d_out;
    short* w_bf16 = (short*)d_ws;

    convert_w_kernel<<<dim3(64), dim3(256), 0, stream>>>(out_w, w_bf16);

    const size_t need = 131072 + (size_t)NROWS * 256 * 2;  // W + att = ~100.2 MB
    if (ws_size >= need) {
        short* att = w_bf16 + 65536;   // after the 128KB bf16 W
        attn_kernel<<<dim3(12800), dim3(128), 0, stream>>>(
            x, qkv_w, qkv_b, pos_encode, pos_index, att);
        conv_kernel<<<dim3(1280), dim3(256), 0, stream>>>(att, w_bf16, y);
    } else {
        patchsa_fused<<<dim3(B_ * NPW), dim3(256), 0, stream>>>(
            x, qkv_w, qkv_b, pos_encode, w_bf16, pos_index, y);
    }
}